// Round 1
// baseline (620.510 us; speedup 1.0000x reference)
//
#include <hip/hip_runtime.h>

#define TB 2
#define TT 2048
#define TC 1024
#define TH 16
#define THD 64
#define LNEPS 1e-5f

typedef _Float16 f16;
typedef __attribute__((ext_vector_type(8))) _Float16 f16x8;
typedef __attribute__((ext_vector_type(4))) _Float16 f16x4;
typedef __attribute__((ext_vector_type(4))) float f32x4;

__device__ __forceinline__ f32x4 mfma_16x16x32(f16x8 a, f16x8 b, f32x4 c) {
    return __builtin_amdgcn_mfma_f32_16x16x32_f16(a, b, c, 0, 0, 0);
}

// ---------------- LayerNorm: fp32 in -> f16 out, one wave per row (C=1024) ----
__global__ __launch_bounds__(256) void ln_kernel(const float* __restrict__ x,
                                                 const float* __restrict__ w,
                                                 const float* __restrict__ bsrc,
                                                 f16* __restrict__ out) {
    int row  = blockIdx.x * 4 + (threadIdx.x >> 6);
    int lane = threadIdx.x & 63;
    const float4* xr = (const float4*)(x + (size_t)row * TC);
    float4 v[4];
    float s = 0.f, ss = 0.f;
#pragma unroll
    for (int i = 0; i < 4; i++) {
        v[i] = xr[i * 64 + lane];
        s  += v[i].x + v[i].y + v[i].z + v[i].w;
        ss += v[i].x * v[i].x + v[i].y * v[i].y + v[i].z * v[i].z + v[i].w * v[i].w;
    }
#pragma unroll
    for (int off = 32; off > 0; off >>= 1) {
        s  += __shfl_xor(s, off);
        ss += __shfl_xor(ss, off);
    }
    float mean = s * (1.f / TC);
    float var  = ss * (1.f / TC) - mean * mean;
    float rstd = rsqrtf(var + LNEPS);
    const float4* wv = (const float4*)w;
    const float4* bv = (const float4*)bsrc;
    f16x4* ov = (f16x4*)(out + (size_t)row * TC);
#pragma unroll
    for (int i = 0; i < 4; i++) {
        int idx = i * 64 + lane;
        float4 wc = wv[idx], bc = bv[idx];
        f16x4 o;
        o[0] = (f16)((v[i].x - mean) * rstd * wc.x + bc.x);
        o[1] = (f16)((v[i].y - mean) * rstd * wc.y + bc.y);
        o[2] = (f16)((v[i].z - mean) * rstd * wc.z + bc.z);
        o[3] = (f16)((v[i].w - mean) * rstd * wc.w + bc.w);
        ov[idx] = o;
    }
}

// ---------------- fp32 -> f16 convert (n4 = element_count/4) ------------------
__global__ void cvt_kernel(const float* __restrict__ src, f16* __restrict__ dst, int n4) {
    int i = blockIdx.x * blockDim.x + threadIdx.x;
    if (i < n4) {
        float4 v = ((const float4*)src)[i];
        f16x4 o;
        o[0] = (f16)v.x; o[1] = (f16)v.y; o[2] = (f16)v.z; o[3] = (f16)v.w;
        ((f16x4*)dst)[i] = o;
    }
}

// ---------------- GEMM: C[M,N] = A[M,K] * W[N,K]^T + bias (+epilogue) ---------
// EPI 0: out f16 = acc + bias
// EPI 1: out f32 = acc + bias + res
// EPI 2: out f16 = gelu_exact(acc + bias)
template <int BM, int BN, int EPI>
__global__ __launch_bounds__(256) void gemm_kernel(const f16* __restrict__ A,
                                                   const f16* __restrict__ W,
                                                   const float* __restrict__ bias,
                                                   const float* __restrict__ res,
                                                   void* __restrict__ outp,
                                                   int M, int N, int K) {
    constexpr int BK = 32;
    __shared__ __align__(16) f16 sA[BM * BK];
    __shared__ __align__(16) f16 sB[BN * BK];
    const int t  = threadIdx.x;
    const int m0 = blockIdx.y * BM;
    const int n0 = blockIdx.x * BN;
    const int wid = t >> 6, lane = t & 63;
    const int wr = wid >> 1, wc = wid & 1;
    constexpr int WM = BM / 2, WN = BN / 2;
    constexpr int MI = WM / 16, NI = WN / 16;
    f32x4 acc[MI][NI];
#pragma unroll
    for (int i = 0; i < MI; i++)
#pragma unroll
        for (int j = 0; j < NI; j++) acc[i][j] = (f32x4){0.f, 0.f, 0.f, 0.f};
    const int quad = lane >> 4, l15 = lane & 15;

    for (int k0 = 0; k0 < K; k0 += BK) {
#pragma unroll
        for (int i = 0; i < BM * 4 / 256; i++) {
            int idx = t + i * 256;
            int r = idx >> 2, cb = (idx & 3) << 3;
            *(uint4*)&sA[r * BK + cb] = *(const uint4*)&A[(size_t)(m0 + r) * K + k0 + cb];
        }
#pragma unroll
        for (int i = 0; i < BN * 4 / 256; i++) {
            int idx = t + i * 256;
            int r = idx >> 2, cb = (idx & 3) << 3;
            *(uint4*)&sB[r * BK + cb] = *(const uint4*)&W[(size_t)(n0 + r) * K + k0 + cb];
        }
        __syncthreads();
        f16x8 af[MI], bf[NI];
#pragma unroll
        for (int i = 0; i < MI; i++)
            af[i] = *(const f16x8*)&sA[(wr * WM + i * 16 + l15) * BK + quad * 8];
#pragma unroll
        for (int j = 0; j < NI; j++)
            bf[j] = *(const f16x8*)&sB[(wc * WN + j * 16 + l15) * BK + quad * 8];
#pragma unroll
        for (int i = 0; i < MI; i++)
#pragma unroll
            for (int j = 0; j < NI; j++)
                acc[i][j] = mfma_16x16x32(af[i], bf[j], acc[i][j]);
        __syncthreads();
    }

#pragma unroll
    for (int i = 0; i < MI; i++) {
#pragma unroll
        for (int j = 0; j < NI; j++) {
            int col   = n0 + wc * WN + j * 16 + l15;
            int rbase = m0 + wr * WM + i * 16 + quad * 4;
            float bvv = bias[col];
#pragma unroll
            for (int r = 0; r < 4; r++) {
                size_t idx = (size_t)(rbase + r) * N + col;
                float v = acc[i][j][r] + bvv;
                if constexpr (EPI == 0) {
                    ((f16*)outp)[idx] = (f16)v;
                } else if constexpr (EPI == 1) {
                    ((float*)outp)[idx] = v + res[idx];
                } else {
                    ((f16*)outp)[idx] = (f16)(0.5f * v * (1.f + erff(v * 0.70710678118f)));
                }
            }
        }
    }
}

// ---------------- V transpose: (B*T, C) f16 -> (B, C, T) f16 ------------------
__global__ __launch_bounds__(256) void transpose_kernel(const f16* __restrict__ in,
                                                        f16* __restrict__ out) {
    __shared__ f16 tile[32][33];
    int bt = blockIdx.x;
    int b  = bt / (TT / 32);
    int t0 = (bt % (TT / 32)) * 32;
    int c0 = blockIdx.y * 32;
    int tx = threadIdx.x & 31;
    int ty = threadIdx.x >> 5;  // 0..7
    for (int r = ty; r < 32; r += 8)
        tile[r][tx] = in[(size_t)(b * TT + t0 + r) * TC + c0 + tx];
    __syncthreads();
    for (int r = ty; r < 32; r += 8)
        out[(size_t)(b * TC + c0 + r) * TT + t0 + tx] = tile[tx][r];
}

// ---------------- Flash-style causal attention --------------------------------
// One wave per 16-row Q tile. q,k: (B*T, C) f16. vT: (B, C, T) f16. y: (B*T, C) f16.
__global__ __launch_bounds__(256) void attn_kernel(const f16* __restrict__ qg,
                                                   const f16* __restrict__ kg,
                                                   const f16* __restrict__ vtg,
                                                   f16* __restrict__ yg) {
    __shared__ __align__(16) f16 pl[4][16 * 32];
    int wid  = threadIdx.x >> 6, lane = threadIdx.x & 63;
    int g    = blockIdx.x * 4 + wid;
    int bh   = g >> 7;          // / (T/16 = 128)
    int qt   = g & 127;
    int b    = bh >> 4, h = bh & 15;
    int q0   = qt * 16;
    int quad = lane >> 4, l15 = lane & 15;

    const f16* qbase = qg + (size_t)(b * TT + q0 + l15) * TC + h * THD + quad * 8;
    f16x8 qa0 = *(const f16x8*)qbase;
    f16x8 qa1 = *(const f16x8*)(qbase + 32);

    f32x4 o[4];
#pragma unroll
    for (int j = 0; j < 4; j++) o[j] = (f32x4){0.f, 0.f, 0.f, 0.f};
    float mrow[4], lrow[4];
#pragma unroll
    for (int r = 0; r < 4; r++) { mrow[r] = -__builtin_inff(); lrow[r] = 0.f; }

    f16* plw = pl[wid];
    int kend = q0 + 15;
    for (int k0 = 0; k0 <= kend; k0 += 32) {
        const f16* kb = kg + (size_t)(b * TT + k0 + l15) * TC + h * THD + quad * 8;
        f16x8 k0lo = *(const f16x8*)kb;
        f16x8 k0hi = *(const f16x8*)(kb + 32);
        f16x8 k1lo = *(const f16x8*)(kb + (size_t)16 * TC);
        f16x8 k1hi = *(const f16x8*)(kb + (size_t)16 * TC + 32);
        f32x4 s0 = (f32x4){0.f, 0.f, 0.f, 0.f};
        f32x4 s1 = (f32x4){0.f, 0.f, 0.f, 0.f};
        s0 = mfma_16x16x32(qa0, k0lo, s0);
        s0 = mfma_16x16x32(qa1, k0hi, s0);
        s1 = mfma_16x16x32(qa0, k1lo, s1);
        s1 = mfma_16x16x32(qa1, k1hi, s1);
        int key0 = k0 + l15, key1 = key0 + 16;
#pragma unroll
        for (int r = 0; r < 4; r++) {
            int qrow = q0 + quad * 4 + r;
            float v0 = (key0 <= qrow) ? s0[r] * 0.125f : -__builtin_inff();
            float v1 = (key1 <= qrow) ? s1[r] * 0.125f : -__builtin_inff();
            float mx = fmaxf(v0, v1);
            mx = fmaxf(mx, __shfl_xor(mx, 1));
            mx = fmaxf(mx, __shfl_xor(mx, 2));
            mx = fmaxf(mx, __shfl_xor(mx, 4));
            mx = fmaxf(mx, __shfl_xor(mx, 8));
            float mnew  = fmaxf(mrow[r], mx);
            float alpha = __expf(mrow[r] - mnew);
            float p0 = __expf(v0 - mnew);
            float p1 = __expf(v1 - mnew);
            float sum = p0 + p1;
            sum += __shfl_xor(sum, 1);
            sum += __shfl_xor(sum, 2);
            sum += __shfl_xor(sum, 4);
            sum += __shfl_xor(sum, 8);
            lrow[r] = lrow[r] * alpha + sum;
            mrow[r] = mnew;
            o[0][r] *= alpha; o[1][r] *= alpha; o[2][r] *= alpha; o[3][r] *= alpha;
            plw[(quad * 4 + r) * 32 + l15]      = (f16)p0;
            plw[(quad * 4 + r) * 32 + 16 + l15] = (f16)p1;
        }
        __asm__ volatile("s_waitcnt lgkmcnt(0)" ::: "memory");
        f16x8 pa = *(const f16x8*)&plw[l15 * 32 + quad * 8];
        const f16* vb = vtg + (size_t)(bh * THD + l15) * TT + k0 + quad * 8;
#pragma unroll
        for (int j = 0; j < 4; j++) {
            f16x8 vf = *(const f16x8*)(vb + (size_t)j * 16 * TT);
            o[j] = mfma_16x16x32(pa, vf, o[j]);
        }
    }
#pragma unroll
    for (int r = 0; r < 4; r++) {
        float inv = 1.f / lrow[r];
        size_t base = (size_t)(b * TT + q0 + quad * 4 + r) * TC + h * THD + l15;
#pragma unroll
        for (int j = 0; j < 4; j++)
            yg[base + j * 16] = (f16)(o[j][r] * inv);
    }
}

// ------------------------------------------------------------------------------
extern "C" void kernel_launch(void* const* d_in, const int* in_sizes, int n_in,
                              void* d_out, int out_size, void* d_ws, size_t ws_size,
                              hipStream_t stream) {
    const float* x    = (const float*)d_in[0];
    const float* ln1w = (const float*)d_in[1];
    const float* ln1b = (const float*)d_in[2];
    const float* ln2w = (const float*)d_in[3];
    const float* ln2b = (const float*)d_in[4];
    const float* Wq   = (const float*)d_in[5];
    const float* bq   = (const float*)d_in[6];
    const float* Wk   = (const float*)d_in[7];
    const float* bk   = (const float*)d_in[8];
    const float* Wv   = (const float*)d_in[9];
    const float* bv   = (const float*)d_in[10];
    const float* Wp   = (const float*)d_in[11];
    const float* bp   = (const float*)d_in[12];
    const float* W1   = (const float*)d_in[13];
    const float* b1   = (const float*)d_in[14];
    const float* W2   = (const float*)d_in[15];
    const float* b2   = (const float*)d_in[16];

    char* ws = (char*)d_ws;
    const size_t MB = 1024 * 1024;
    f16* hb  = (f16*)(ws + 0);         // 8MB; reused as yb after QKV
    f16* qb  = (f16*)(ws + 8 * MB);    // 8MB; reused as h2b after attention
    f16* kb  = (f16*)(ws + 16 * MB);   // 8MB
    f16* vb  = (f16*)(ws + 24 * MB);   // 8MB
    f16* vT  = (f16*)(ws + 32 * MB);   // 8MB
    f16* mb  = (f16*)(ws + 16 * MB);   // 32MB (16..48), reuses kb/vb/vT post-attention
    f16* Wqb = (f16*)(ws + 48 * MB);
    f16* Wkb = (f16*)(ws + 50 * MB);
    f16* Wvb = (f16*)(ws + 52 * MB);
    f16* Wpb = (f16*)(ws + 54 * MB);
    f16* W1b = (f16*)(ws + 56 * MB);   // 8MB
    f16* W2b = (f16*)(ws + 64 * MB);   // 8MB -> total 72MB
    f16* yb  = hb;
    f16* h2b = qb;
    float* x1 = (float*)d_out;

    // LN1 + weight casts
    ln_kernel<<<1024, 256, 0, stream>>>(x, ln1w, ln1b, hb);
    cvt_kernel<<<1024, 256, 0, stream>>>(Wq, Wqb, 262144);
    cvt_kernel<<<1024, 256, 0, stream>>>(Wk, Wkb, 262144);
    cvt_kernel<<<1024, 256, 0, stream>>>(Wv, Wvb, 262144);
    cvt_kernel<<<1024, 256, 0, stream>>>(Wp, Wpb, 262144);
    cvt_kernel<<<4096, 256, 0, stream>>>(W1, W1b, 1048576);
    cvt_kernel<<<4096, 256, 0, stream>>>(W2, W2b, 1048576);

    dim3 g64(TC / 64, (TB * TT) / 128);
    // QKV projections
    gemm_kernel<128, 64, 0><<<g64, 256, 0, stream>>>(hb, Wqb, bq, nullptr, qb, TB * TT, TC, TC);
    gemm_kernel<128, 64, 0><<<g64, 256, 0, stream>>>(hb, Wkb, bk, nullptr, kb, TB * TT, TC, TC);
    gemm_kernel<128, 64, 0><<<g64, 256, 0, stream>>>(hb, Wvb, bv, nullptr, vb, TB * TT, TC, TC);
    // V transpose to (B, C, T)
    transpose_kernel<<<dim3(TB * TT / 32, TC / 32), 256, 0, stream>>>(vb, vT);
    // causal attention
    attn_kernel<<<1024, 256, 0, stream>>>(qb, kb, vT, yb);
    // output projection + residual -> x1 (fp32, in d_out)
    gemm_kernel<128, 64, 1><<<g64, 256, 0, stream>>>(yb, Wpb, bp, x, x1, TB * TT, TC, TC);
    // LN2
    ln_kernel<<<1024, 256, 0, stream>>>(x1, ln2w, ln2b, h2b);
    // MLP up + exact GELU
    gemm_kernel<128, 128, 2><<<dim3(4 * TC / 128, (TB * TT) / 128), 256, 0, stream>>>(
        h2b, W1b, b1, nullptr, mb, TB * TT, 4 * TC, TC);
    // MLP down + residual (in-place on d_out)
    gemm_kernel<128, 64, 1><<<g64, 256, 0, stream>>>(mb, W2b, b2, x1, x1, TB * TT, TC, 4 * TC);
}

// Round 2
// 503.016 us; speedup vs baseline: 1.2336x; 1.2336x over previous
//
#include <hip/hip_runtime.h>

#define TB 2
#define TT 2048
#define TC 1024
#define TH 16
#define THD 64
#define LNEPS 1e-5f

typedef _Float16 f16;
typedef __attribute__((ext_vector_type(8))) _Float16 f16x8;
typedef __attribute__((ext_vector_type(4))) _Float16 f16x4;
typedef __attribute__((ext_vector_type(4))) float f32x4;

__device__ __forceinline__ f32x4 mfma_16x16x32(f16x8 a, f16x8 b, f32x4 c) {
    return __builtin_amdgcn_mfma_f32_16x16x32_f16(a, b, c, 0, 0, 0);
}

__device__ __forceinline__ void load_lds16(const f16* g, f16* l) {
    __builtin_amdgcn_global_load_lds(
        (const __attribute__((address_space(1))) unsigned int*)g,
        (__attribute__((address_space(3))) unsigned int*)l, 16, 0, 0);
}

// ---------------- LayerNorm: fp32 in -> f16 out, one wave per row (C=1024) ----
__global__ __launch_bounds__(256) void ln_kernel(const float* __restrict__ x,
                                                 const float* __restrict__ w,
                                                 const float* __restrict__ bsrc,
                                                 f16* __restrict__ out) {
    int row  = blockIdx.x * 4 + (threadIdx.x >> 6);
    int lane = threadIdx.x & 63;
    const float4* xr = (const float4*)(x + (size_t)row * TC);
    float4 v[4];
    float s = 0.f, ss = 0.f;
#pragma unroll
    for (int i = 0; i < 4; i++) {
        v[i] = xr[i * 64 + lane];
        s  += v[i].x + v[i].y + v[i].z + v[i].w;
        ss += v[i].x * v[i].x + v[i].y * v[i].y + v[i].z * v[i].z + v[i].w * v[i].w;
    }
#pragma unroll
    for (int off = 32; off > 0; off >>= 1) {
        s  += __shfl_xor(s, off);
        ss += __shfl_xor(ss, off);
    }
    float mean = s * (1.f / TC);
    float var  = ss * (1.f / TC) - mean * mean;
    float rstd = rsqrtf(var + LNEPS);
    const float4* wv = (const float4*)w;
    const float4* bv = (const float4*)bsrc;
    f16x4* ov = (f16x4*)(out + (size_t)row * TC);
#pragma unroll
    for (int i = 0; i < 4; i++) {
        int idx = i * 64 + lane;
        float4 wc = wv[idx], bc = bv[idx];
        f16x4 o;
        o[0] = (f16)((v[i].x - mean) * rstd * wc.x + bc.x);
        o[1] = (f16)((v[i].y - mean) * rstd * wc.y + bc.y);
        o[2] = (f16)((v[i].z - mean) * rstd * wc.z + bc.z);
        o[3] = (f16)((v[i].w - mean) * rstd * wc.w + bc.w);
        ov[idx] = o;
    }
}

// ---------------- fp32 -> f16 convert (n4 = element_count/4) ------------------
__global__ void cvt_kernel(const float* __restrict__ src, f16* __restrict__ dst, int n4) {
    int i = blockIdx.x * blockDim.x + threadIdx.x;
    if (i < n4) {
        float4 v = ((const float4*)src)[i];
        f16x4 o;
        o[0] = (f16)v.x; o[1] = (f16)v.y; o[2] = (f16)v.z; o[3] = (f16)v.w;
        ((f16x4*)dst)[i] = o;
    }
}

// ---------------- GEMM: C[M,N] = A[M,K] * W[N,K]^T + bias (+epilogue) ---------
// EPI 0: out f16 = acc + bias
// EPI 1: out f32 = acc + bias + res
// EPI 2: out f16 = gelu_exact(acc + bias)
template <int BM, int BN, int EPI>
__global__ __launch_bounds__(256) void gemm_kernel(const f16* __restrict__ A,
                                                   const f16* __restrict__ W,
                                                   const float* __restrict__ bias,
                                                   const float* __restrict__ res,
                                                   void* __restrict__ outp,
                                                   int M, int N, int K) {
    constexpr int BK = 32;
    __shared__ __align__(16) f16 sA[BM * BK];
    __shared__ __align__(16) f16 sB[BN * BK];
    const int t  = threadIdx.x;
    const int m0 = blockIdx.y * BM;
    const int n0 = blockIdx.x * BN;
    const int wid = t >> 6, lane = t & 63;
    const int wr = wid >> 1, wc = wid & 1;
    constexpr int WM = BM / 2, WN = BN / 2;
    constexpr int MI = WM / 16, NI = WN / 16;
    f32x4 acc[MI][NI];
#pragma unroll
    for (int i = 0; i < MI; i++)
#pragma unroll
        for (int j = 0; j < NI; j++) acc[i][j] = (f32x4){0.f, 0.f, 0.f, 0.f};
    const int quad = lane >> 4, l15 = lane & 15;
    // staging addresses: thread t handles 16B chunk idx = t + i*256
    // global row = idx>>2, col byte-block = (idx&3)*8 ; LDS dest = idx*8 f16 (lane-contiguous x16B)

    for (int k0 = 0; k0 < K; k0 += BK) {
#pragma unroll
        for (int i = 0; i < BM * BK / 2048; i++) {
            int idx = t + i * 256;
            int r = idx >> 2, cb = (idx & 3) << 3;
            load_lds16(&A[(size_t)(m0 + r) * K + k0 + cb], &sA[idx * 8]);
        }
#pragma unroll
        for (int i = 0; i < BN * BK / 2048; i++) {
            int idx = t + i * 256;
            int r = idx >> 2, cb = (idx & 3) << 3;
            load_lds16(&W[(size_t)(n0 + r) * K + k0 + cb], &sB[idx * 8]);
        }
        __syncthreads();
        f16x8 af[MI], bf[NI];
#pragma unroll
        for (int i = 0; i < MI; i++)
            af[i] = *(const f16x8*)&sA[(wr * WM + i * 16 + l15) * BK + quad * 8];
#pragma unroll
        for (int j = 0; j < NI; j++)
            bf[j] = *(const f16x8*)&sB[(wc * WN + j * 16 + l15) * BK + quad * 8];
#pragma unroll
        for (int i = 0; i < MI; i++)
#pragma unroll
            for (int j = 0; j < NI; j++)
                acc[i][j] = mfma_16x16x32(af[i], bf[j], acc[i][j]);
        __syncthreads();
    }

#pragma unroll
    for (int i = 0; i < MI; i++) {
#pragma unroll
        for (int j = 0; j < NI; j++) {
            int col   = n0 + wc * WN + j * 16 + l15;
            int rbase = m0 + wr * WM + i * 16 + quad * 4;
            float bvv = bias[col];
#pragma unroll
            for (int r = 0; r < 4; r++) {
                size_t idx = (size_t)(rbase + r) * N + col;
                float v = acc[i][j][r] + bvv;
                if constexpr (EPI == 0) {
                    ((f16*)outp)[idx] = (f16)v;
                } else if constexpr (EPI == 1) {
                    ((float*)outp)[idx] = v + res[idx];
                } else {
                    ((f16*)outp)[idx] = (f16)(0.5f * v * (1.f + erff(v * 0.70710678118f)));
                }
            }
        }
    }
}

// ---------------- V transpose: (B*T, C) f16 -> (B, C, T) f16 ------------------
__global__ __launch_bounds__(256) void transpose_kernel(const f16* __restrict__ in,
                                                        f16* __restrict__ out) {
    __shared__ f16 tile[32][33];
    int bt = blockIdx.x;
    int b  = bt / (TT / 32);
    int t0 = (bt % (TT / 32)) * 32;
    int c0 = blockIdx.y * 32;
    int tx = threadIdx.x & 31;
    int ty = threadIdx.x >> 5;  // 0..7
    for (int r = ty; r < 32; r += 8)
        tile[r][tx] = in[(size_t)(b * TT + t0 + r) * TC + c0 + tx];
    __syncthreads();
    for (int r = ty; r < 32; r += 8)
        out[(size_t)(b * TC + c0 + r) * TT + t0 + tx] = tile[tx][r];
}

// ---------------- Flash-style causal attention (S^T formulation) --------------
// One wave per 16-query tile. Computes S^T = K·Q^T so softmax stats are
// per-lane-column (query = lane&15): cross-quad reduce = 2 shuffles.
// O^T = V^T · P^T accumulated in C-layout (col=query), epilogue packed 8B.
__global__ __launch_bounds__(256) void attn_kernel(const f16* __restrict__ qg,
                                                   const f16* __restrict__ kg,
                                                   const f16* __restrict__ vtg,
                                                   f16* __restrict__ yg) {
    __shared__ __align__(16) f16 pl[4][16 * 32];  // per-wave P^T as [query][key32]
    int wid  = threadIdx.x >> 6, lane = threadIdx.x & 63;
    int g    = blockIdx.x * 4 + wid;
    int bh   = g >> 7;
    int w    = g & 127;
    // balanced mapping: pair small qt with large qt so per-block work ~const
    int qt   = (w & 1) ? (127 - (w >> 1)) : (w >> 1);
    int b    = bh >> 4, h = bh & 15;
    int q0   = qt * 16;
    int quad = lane >> 4, l15 = lane & 15;

    // Q fragment = B operand of S^T: B[d=quad*8+j][query=l15], pre-scaled by 1/8
    const f16* qbase = qg + (size_t)(b * TT + q0 + l15) * TC + h * THD + quad * 8;
    f16x8 qa0 = *(const f16x8*)qbase;
    f16x8 qa1 = *(const f16x8*)(qbase + 32);
#pragma unroll
    for (int j = 0; j < 8; j++) { qa0[j] = qa0[j] * (f16)0.125f; qa1[j] = qa1[j] * (f16)0.125f; }

    f32x4 o[4];  // O^T accumulators: d-tile j: rows d=j*16+quad*4+r, col query=l15
#pragma unroll
    for (int j = 0; j < 4; j++) o[j] = (f32x4){0.f, 0.f, 0.f, 0.f};
    float mcol = -__builtin_inff(), lcol = 0.f;  // per-query (lane) stats

    f16* plw = pl[wid];
    int kend = q0 + 15;
    for (int k0 = 0; k0 <= kend; k0 += 32) {
        // K fragments = A operand: A[key=l15][d=quad*8+j]
        const f16* kb = kg + (size_t)(b * TT + k0 + l15) * TC + h * THD + quad * 8;
        f16x8 k0lo = *(const f16x8*)kb;
        f16x8 k0hi = *(const f16x8*)(kb + 32);
        f16x8 k1lo = *(const f16x8*)(kb + (size_t)16 * TC);
        f16x8 k1hi = *(const f16x8*)(kb + (size_t)16 * TC + 32);
        f32x4 s0 = (f32x4){0.f, 0.f, 0.f, 0.f};
        f32x4 s1 = (f32x4){0.f, 0.f, 0.f, 0.f};
        s0 = mfma_16x16x32(k0lo, qa0, s0);
        s0 = mfma_16x16x32(k0hi, qa1, s0);
        s1 = mfma_16x16x32(k1lo, qa0, s1);
        s1 = mfma_16x16x32(k1hi, qa1, s1);
        // rows of s0: key = k0+quad*4+r ; s1: +16. col: query = q0+l15.
        int query = q0 + l15;
        float v0[4], v1[4];
        float lm = -__builtin_inff();
#pragma unroll
        for (int r = 0; r < 4; r++) {
            int key = k0 + quad * 4 + r;
            v0[r] = (key <= query) ? s0[r] : -__builtin_inff();
            v1[r] = (key + 16 <= query) ? s1[r] : -__builtin_inff();
            lm = fmaxf(lm, fmaxf(v0[r], v1[r]));
        }
        lm = fmaxf(lm, __shfl_xor(lm, 16));
        lm = fmaxf(lm, __shfl_xor(lm, 32));
        float mnew  = fmaxf(mcol, lm);
        float alpha = __expf(mcol - mnew);
        float sum = 0.f;
        f16x4 pw0, pw1;
#pragma unroll
        for (int r = 0; r < 4; r++) {
            float p0 = __expf(v0[r] - mnew);
            float p1 = __expf(v1[r] - mnew);
            sum += p0 + p1;
            pw0[r] = (f16)p0;
            pw1[r] = (f16)p1;
        }
        sum += __shfl_xor(sum, 16);
        sum += __shfl_xor(sum, 32);
        lcol = lcol * alpha + sum;
        mcol = mnew;
#pragma unroll
        for (int j = 0; j < 4; j++) {
            o[j][0] *= alpha; o[j][1] *= alpha; o[j][2] *= alpha; o[j][3] *= alpha;
        }
        // store P^T as [query][key]: 2x 8B writes
        *(f16x4*)&plw[l15 * 32 + quad * 4]      = pw0;
        *(f16x4*)&plw[l15 * 32 + 16 + quad * 4] = pw1;
        __asm__ volatile("s_waitcnt lgkmcnt(0)" ::: "memory");
        // B operand of O^T: B[key=quad*8+j][query=l15]
        f16x8 pb = *(const f16x8*)&plw[l15 * 32 + quad * 8];
        // A operand: V^T[d=l15][key=quad*8+j] per d-tile
        const f16* vb = vtg + (size_t)(bh * THD + l15) * TT + k0 + quad * 8;
#pragma unroll
        for (int j = 0; j < 4; j++) {
            f16x8 vf = *(const f16x8*)(vb + (size_t)j * 16 * TT);
            o[j] = mfma_16x16x32(vf, pb, o[j]);
        }
    }
    float inv = 1.f / lcol;
    size_t rowbase = (size_t)(b * TT + q0 + l15) * TC + h * THD;
#pragma unroll
    for (int j = 0; j < 4; j++) {
        f16x4 ov;
#pragma unroll
        for (int r = 0; r < 4; r++) ov[r] = (f16)(o[j][r] * inv);
        *(f16x4*)&yg[rowbase + j * 16 + quad * 4] = ov;
    }
}

// ------------------------------------------------------------------------------
extern "C" void kernel_launch(void* const* d_in, const int* in_sizes, int n_in,
                              void* d_out, int out_size, void* d_ws, size_t ws_size,
                              hipStream_t stream) {
    const float* x    = (const float*)d_in[0];
    const float* ln1w = (const float*)d_in[1];
    const float* ln1b = (const float*)d_in[2];
    const float* ln2w = (const float*)d_in[3];
    const float* ln2b = (const float*)d_in[4];
    const float* Wq   = (const float*)d_in[5];
    const float* bq   = (const float*)d_in[6];
    const float* Wk   = (const float*)d_in[7];
    const float* bk   = (const float*)d_in[8];
    const float* Wv   = (const float*)d_in[9];
    const float* bv   = (const float*)d_in[10];
    const float* Wp   = (const float*)d_in[11];
    const float* bp   = (const float*)d_in[12];
    const float* W1   = (const float*)d_in[13];
    const float* b1   = (const float*)d_in[14];
    const float* W2   = (const float*)d_in[15];
    const float* b2   = (const float*)d_in[16];

    char* ws = (char*)d_ws;
    const size_t MB = 1024 * 1024;
    f16* hb  = (f16*)(ws + 0);         // 8MB; reused as yb after QKV
    f16* qb  = (f16*)(ws + 8 * MB);    // 8MB; reused as h2b after attention
    f16* kb  = (f16*)(ws + 16 * MB);   // 8MB
    f16* vb  = (f16*)(ws + 24 * MB);   // 8MB
    f16* vT  = (f16*)(ws + 32 * MB);   // 8MB
    f16* mb  = (f16*)(ws + 16 * MB);   // 32MB (16..48), reuses kb/vb/vT post-attention
    f16* Wqb = (f16*)(ws + 48 * MB);
    f16* Wkb = (f16*)(ws + 50 * MB);
    f16* Wvb = (f16*)(ws + 52 * MB);
    f16* Wpb = (f16*)(ws + 54 * MB);
    f16* W1b = (f16*)(ws + 56 * MB);   // 8MB
    f16* W2b = (f16*)(ws + 64 * MB);   // 8MB -> total 72MB
    f16* yb  = hb;
    f16* h2b = qb;
    float* x1 = (float*)d_out;

    // LN1 + weight casts
    ln_kernel<<<1024, 256, 0, stream>>>(x, ln1w, ln1b, hb);
    cvt_kernel<<<1024, 256, 0, stream>>>(Wq, Wqb, 262144);
    cvt_kernel<<<1024, 256, 0, stream>>>(Wk, Wkb, 262144);
    cvt_kernel<<<1024, 256, 0, stream>>>(Wv, Wvb, 262144);
    cvt_kernel<<<1024, 256, 0, stream>>>(Wp, Wpb, 262144);
    cvt_kernel<<<4096, 256, 0, stream>>>(W1, W1b, 1048576);
    cvt_kernel<<<4096, 256, 0, stream>>>(W2, W2b, 1048576);

    dim3 g64(TC / 64, (TB * TT) / 128);
    // QKV projections
    gemm_kernel<128, 64, 0><<<g64, 256, 0, stream>>>(hb, Wqb, bq, nullptr, qb, TB * TT, TC, TC);
    gemm_kernel<128, 64, 0><<<g64, 256, 0, stream>>>(hb, Wkb, bk, nullptr, kb, TB * TT, TC, TC);
    gemm_kernel<128, 64, 0><<<g64, 256, 0, stream>>>(hb, Wvb, bv, nullptr, vb, TB * TT, TC, TC);
    // V transpose to (B, C, T)
    transpose_kernel<<<dim3(TB * TT / 32, TC / 32), 256, 0, stream>>>(vb, vT);
    // causal attention
    attn_kernel<<<1024, 256, 0, stream>>>(qb, kb, vT, yb);
    // output projection + residual -> x1 (fp32, in d_out)
    gemm_kernel<128, 64, 1><<<g64, 256, 0, stream>>>(yb, Wpb, bp, x, x1, TB * TT, TC, TC);
    // LN2
    ln_kernel<<<1024, 256, 0, stream>>>(x1, ln2w, ln2b, h2b);
    // MLP up + exact GELU
    gemm_kernel<128, 128, 2><<<dim3(4 * TC / 128, (TB * TT) / 128), 256, 0, stream>>>(
        h2b, W1b, b1, nullptr, mb, TB * TT, 4 * TC, TC);
    // MLP down + residual (in-place on d_out)
    gemm_kernel<128, 64, 1><<<g64, 256, 0, stream>>>(mb, W2b, b2, x1, x1, TB * TT, TC, 4 * TC);
}

// Round 4
// 396.290 us; speedup vs baseline: 1.5658x; 1.2693x over previous
//
#include <hip/hip_runtime.h>

#define TB 2
#define TT 2048
#define TC 1024
#define TH 16
#define THD 64
#define LNEPS 1e-5f

typedef _Float16 f16;
typedef __attribute__((ext_vector_type(8))) _Float16 f16x8;
typedef __attribute__((ext_vector_type(4))) _Float16 f16x4;
typedef __attribute__((ext_vector_type(4))) float f32x4;

__device__ __forceinline__ f32x4 mfma_16x16x32(f16x8 a, f16x8 b, f32x4 c) {
    return __builtin_amdgcn_mfma_f32_16x16x32_f16(a, b, c, 0, 0, 0);
}

__device__ __forceinline__ void load_lds16(const f16* g, f16* l) {
    __builtin_amdgcn_global_load_lds(
        (const __attribute__((address_space(1))) unsigned int*)g,
        (__attribute__((address_space(3))) unsigned int*)l, 16, 0, 0);
}

// ---------------- LayerNorm: fp32 in -> f16 out, one wave per row (C=1024) ----
__global__ __launch_bounds__(256) void ln_kernel(const float* __restrict__ x,
                                                 const float* __restrict__ w,
                                                 const float* __restrict__ bsrc,
                                                 f16* __restrict__ out) {
    int row  = blockIdx.x * 4 + (threadIdx.x >> 6);
    int lane = threadIdx.x & 63;
    const float4* xr = (const float4*)(x + (size_t)row * TC);
    float4 v[4];
    float s = 0.f, ss = 0.f;
#pragma unroll
    for (int i = 0; i < 4; i++) {
        v[i] = xr[i * 64 + lane];
        s  += v[i].x + v[i].y + v[i].z + v[i].w;
        ss += v[i].x * v[i].x + v[i].y * v[i].y + v[i].z * v[i].z + v[i].w * v[i].w;
    }
#pragma unroll
    for (int off = 32; off > 0; off >>= 1) {
        s  += __shfl_xor(s, off);
        ss += __shfl_xor(ss, off);
    }
    float mean = s * (1.f / TC);
    float var  = ss * (1.f / TC) - mean * mean;
    float rstd = rsqrtf(var + LNEPS);
    const float4* wv = (const float4*)w;
    const float4* bv = (const float4*)bsrc;
    f16x4* ov = (f16x4*)(out + (size_t)row * TC);
#pragma unroll
    for (int i = 0; i < 4; i++) {
        int idx = i * 64 + lane;
        float4 wc = wv[idx], bc = bv[idx];
        f16x4 o;
        o[0] = (f16)((v[i].x - mean) * rstd * wc.x + bc.x);
        o[1] = (f16)((v[i].y - mean) * rstd * wc.y + bc.y);
        o[2] = (f16)((v[i].z - mean) * rstd * wc.z + bc.z);
        o[3] = (f16)((v[i].w - mean) * rstd * wc.w + bc.w);
        ov[idx] = o;
    }
}

// ---------------- fused fp32 -> f16 weight convert ----------------------------
// dst layout: Wq(1M) Wk(1M) Wv(1M) Wp(1M) W1(4M) W2(4M) f16 elements, contiguous.
__global__ void cvt_all_kernel(const float* __restrict__ Wq, const float* __restrict__ Wk,
                               const float* __restrict__ Wv, const float* __restrict__ Wp,
                               const float* __restrict__ W1, const float* __restrict__ W2,
                               f16* __restrict__ dst) {
    int i = blockIdx.x * blockDim.x + threadIdx.x;  // x4 units, total 3145728
    const int Q = 262144;                           // 1M elems / 4
    const float* src;
    int j;
    int s = i >> 18;
    if (s < 4) {
        src = (s == 0) ? Wq : (s == 1) ? Wk : (s == 2) ? Wv : Wp;
        j = i & (Q - 1);
    } else if (s < 8) {
        src = W1; j = i - 4 * Q;
    } else {
        src = W2; j = i - 8 * Q;
    }
    float4 v = ((const float4*)src)[j];
    f16x4 o;
    o[0] = (f16)v.x; o[1] = (f16)v.y; o[2] = (f16)v.z; o[3] = (f16)v.w;
    ((f16x4*)dst)[i] = o;
}

// ---------------- GEMM: C[M,N] = A[M,K] * W[N,K]^T + bias (+epilogue) ---------
// EPI 0: out f16 = acc + bias
// EPI 1: out f32 = acc + bias + res
// EPI 2: out f16 = gelu_exact(acc + bias)
// EPI 3: out f16 = acc + bias-select(bq|bk|bv)  (fused QKV, N=3072)
template <int BM, int BN, int EPI>
__global__ __launch_bounds__(256) void gemm_kernel(const f16* __restrict__ A,
                                                   const f16* __restrict__ W,
                                                   const float* __restrict__ bias,
                                                   const float* __restrict__ bias2,
                                                   const float* __restrict__ bias3,
                                                   const float* __restrict__ res,
                                                   void* __restrict__ outp,
                                                   int M, int N, int K) {
    constexpr int BK = 32;
    __shared__ __align__(16) f16 sA[BM * BK];
    __shared__ __align__(16) f16 sB[BN * BK];
    const int t  = threadIdx.x;
    const int m0 = blockIdx.y * BM;
    const int n0 = blockIdx.x * BN;
    const int wid = t >> 6, lane = t & 63;
    const int wr = wid >> 1, wc = wid & 1;
    constexpr int WM = BM / 2, WN = BN / 2;
    constexpr int MI = WM / 16, NI = WN / 16;
    f32x4 acc[MI][NI];
#pragma unroll
    for (int i = 0; i < MI; i++)
#pragma unroll
        for (int j = 0; j < NI; j++) acc[i][j] = (f32x4){0.f, 0.f, 0.f, 0.f};
    const int quad = lane >> 4, l15 = lane & 15;

    for (int k0 = 0; k0 < K; k0 += BK) {
#pragma unroll
        for (int i = 0; i < BM * BK / 2048; i++) {
            int idx = t + i * 256;
            int r = idx >> 2, cb = (idx & 3) << 3;
            load_lds16(&A[(size_t)(m0 + r) * K + k0 + cb], &sA[idx * 8]);
        }
#pragma unroll
        for (int i = 0; i < BN * BK / 2048; i++) {
            int idx = t + i * 256;
            int r = idx >> 2, cb = (idx & 3) << 3;
            load_lds16(&W[(size_t)(n0 + r) * K + k0 + cb], &sB[idx * 8]);
        }
        __syncthreads();
        f16x8 af[MI], bf[NI];
#pragma unroll
        for (int i = 0; i < MI; i++)
            af[i] = *(const f16x8*)&sA[(wr * WM + i * 16 + l15) * BK + quad * 8];
#pragma unroll
        for (int j = 0; j < NI; j++)
            bf[j] = *(const f16x8*)&sB[(wc * WN + j * 16 + l15) * BK + quad * 8];
#pragma unroll
        for (int i = 0; i < MI; i++)
#pragma unroll
            for (int j = 0; j < NI; j++)
                acc[i][j] = mfma_16x16x32(af[i], bf[j], acc[i][j]);
        __syncthreads();
    }

#pragma unroll
    for (int i = 0; i < MI; i++) {
#pragma unroll
        for (int j = 0; j < NI; j++) {
            int col   = n0 + wc * WN + j * 16 + l15;
            int rbase = m0 + wr * WM + i * 16 + quad * 4;
            float bvv;
            if constexpr (EPI == 3)
                bvv = (col < 1024) ? bias[col]
                    : (col < 2048) ? bias2[col - 1024] : bias3[col - 2048];
            else
                bvv = bias[col];
#pragma unroll
            for (int r = 0; r < 4; r++) {
                size_t idx = (size_t)(rbase + r) * N + col;
                float v = acc[i][j][r] + bvv;
                if constexpr (EPI == 0 || EPI == 3) {
                    ((f16*)outp)[idx] = (f16)v;
                } else if constexpr (EPI == 1) {
                    ((float*)outp)[idx] = v + res[idx];
                } else {
                    ((f16*)outp)[idx] = (f16)(0.5f * v * (1.f + erff(v * 0.70710678118f)));
                }
            }
        }
    }
}

// ---------------- V transpose: qkv v-slice (stride 3072) -> (B, C, T) f16 -----
__global__ __launch_bounds__(256) void transpose_kernel(const f16* __restrict__ in,
                                                        f16* __restrict__ out) {
    __shared__ f16 tile[32][33];
    int bt = blockIdx.x;
    int b  = bt / (TT / 32);
    int t0 = (bt % (TT / 32)) * 32;
    int c0 = blockIdx.y * 32;
    int tx = threadIdx.x & 31;
    int ty = threadIdx.x >> 5;  // 0..7
    for (int r = ty; r < 32; r += 8)
        tile[r][tx] = in[(size_t)(b * TT + t0 + r) * 3072 + 2048 + c0 + tx];
    __syncthreads();
    for (int r = ty; r < 32; r += 8)
        out[(size_t)(b * TC + c0 + r) * TT + t0 + tx] = tile[tx][r];
}

// ---------------- Block-cooperative flash attention (S^T formulation) ---------
// Block = 64 queries (4 waves x 16), K/V tiles of 64 keys double-buffered in
// LDS via global_load_lds; online softmax per lane-column (query = lane&15);
// XOR-swizzled LDS layouts -> <=2-way bank conflicts.
__global__ __launch_bounds__(256, 4) void attn_kernel(const f16* __restrict__ qkv,
                                                      const f16* __restrict__ vtg,
                                                      f16* __restrict__ yg) {
    __shared__ __align__(16) f16 sK[2][64 * 64];   // phys chunk = key*8 + (dc ^ (key&7))
    __shared__ __align__(16) f16 sV[2][64 * 64];   // phys chunk = d*8 + (kc ^ (d&7))
    __shared__ __align__(16) f16 pl[4][16 * 64];   // 4e chunk = q*16 + (kq ^ ((q&7)*2))
    const int t    = threadIdx.x;
    const int wid  = t >> 6, lane = t & 63;
    const int quad = lane >> 4, l15 = lane & 15;
    // balanced (bh, qblk) mapping: the 4 blocks {i, i+256, i+512, i+768} that
    // land on one CU get qblk sets summing to a constant (62).
    const int idx = blockIdx.x;
    const int u = idx & 255, r = idx >> 8;
    const int bh = u & 31, rc = u >> 5;
    const int qblk = (r == 0) ? rc : (r == 1) ? 31 - rc : (r == 2) ? 8 + rc : 23 - rc;
    const int b = bh >> 4, h = bh & 15;
    const int q0 = qblk * 64;
    const int q0w = q0 + wid * 16;

    const f16* qptr = qkv + (size_t)(b * TT) * 3072 + h * THD;  // q slice, row stride 3072
    const f16* kptr = qptr + 1024;                              // k slice

    // Q fragment (B operand of S^T): B[d=quad*8+j][query=l15], pre-scaled 1/8
    f16x8 qa0, qa1;
    {
        const f16* qb_ = qptr + (size_t)(q0w + l15) * 3072 + quad * 8;
        qa0 = *(const f16x8*)qb_;
        qa1 = *(const f16x8*)(qb_ + 32);
#pragma unroll
        for (int j = 0; j < 8; j++) { qa0[j] *= (f16)0.125f; qa1[j] *= (f16)0.125f; }
    }

    auto stage = [&](int buf, int k0) {
#pragma unroll
        for (int i = 0; i < 2; i++) {
            int p = t + i * 256;            // chunk index 0..511
            int row = p >> 3, c0 = p & 7;
            int cc = c0 ^ (row & 7);        // swizzled source chunk
            load_lds16(kptr + (size_t)(k0 + row) * 3072 + cc * 8, &sK[buf][p * 8]);
            load_lds16(vtg + (size_t)(bh * THD + row) * TT + k0 + cc * 8, &sV[buf][p * 8]);
        }
    };

    f32x4 o[4];
#pragma unroll
    for (int j = 0; j < 4; j++) o[j] = (f32x4){0.f, 0.f, 0.f, 0.f};
    float mcol = -__builtin_inff(), lsum = 0.f;   // per-query (lane-col) stats
    f16* plw = pl[wid];
    const int sw = (l15 & 7) << 1;
    const int nt = qblk + 1;

    stage(0, 0);
    for (int it = 0; it < nt; it++) {
        const int cur = it & 1;
        __syncthreads();                      // drains tile-it loads (vmcnt)
        if (it + 1 < nt) stage(cur ^ 1, (it + 1) * 64);  // prefetch during compute
        const int k0 = it * 64;
        if (k0 <= q0w + 15) {                 // wave-uniform: skip fully-masked tiles
            const f16* sk = sK[cur];
            f32x4 s[4];
#pragma unroll
            for (int g = 0; g < 4; g++) {
                int key = g * 16 + l15;
                f16x8 klo = *(const f16x8*)&sk[(key * 8 + (quad ^ (l15 & 7))) * 8];
                f16x8 khi = *(const f16x8*)&sk[(key * 8 + ((quad + 4) ^ (l15 & 7))) * 8];
                f32x4 a = (f32x4){0.f, 0.f, 0.f, 0.f};
                a = mfma_16x16x32(klo, qa0, a);
                a = mfma_16x16x32(khi, qa1, a);
                s[g] = a;
            }
            const bool full = (k0 + 63 <= q0w);   // wave-uniform: no masking needed
            // pass 1: mask + per-tile max
            float lm = -__builtin_inff();
#pragma unroll
            for (int g = 0; g < 4; g++) {
#pragma unroll
                for (int rr = 0; rr < 4; rr++) {
                    if (!full) {
                        int key = k0 + g * 16 + quad * 4 + rr;
                        if (key > q0w + l15) s[g][rr] = -__builtin_inff();
                    }
                    lm = fmaxf(lm, s[g][rr]);
                }
            }
            lm = fmaxf(lm, __shfl_xor(lm, 16));
            lm = fmaxf(lm, __shfl_xor(lm, 32));
            float mnew  = fmaxf(mcol, lm);
            float alpha = __expf(mcol - mnew);
            mcol = mnew;
            // pass 2: exp, store P^T, accumulate sum
            float sum = 0.f;
#pragma unroll
            for (int g = 0; g < 4; g++) {
                f16x4 pw;
#pragma unroll
                for (int rr = 0; rr < 4; rr++) {
                    float p = __expf(s[g][rr] - mnew);
                    sum += p;
                    pw[rr] = (f16)p;
                }
                *(f16x4*)&plw[(l15 * 16 + ((g * 4 + quad) ^ sw)) * 4] = pw;
            }
            sum += __shfl_xor(sum, 16);
            sum += __shfl_xor(sum, 32);
            lsum = lsum * alpha + sum;
#pragma unroll
            for (int j = 0; j < 4; j++) {
                o[j][0] *= alpha; o[j][1] *= alpha; o[j][2] *= alpha; o[j][3] *= alpha;
            }
            __asm__ volatile("s_waitcnt lgkmcnt(0)" ::: "memory");
            const f16* sv = sV[cur];
#pragma unroll
            for (int hh = 0; hh < 2; hh++) {
                // B operand: P^T[key=hh*32+quad*8+j][query=l15] (row-offset + swizzle)
                f16x8 pb = *(const f16x8*)&plw[(l15 * 16 + ((hh * 8 + quad * 2) ^ sw)) * 4];
#pragma unroll
                for (int j = 0; j < 4; j++) {
                    int d = j * 16 + l15;
                    f16x8 vf = *(const f16x8*)&sv[(d * 8 + ((4 * hh + quad) ^ (l15 & 7))) * 8];
                    o[j] = mfma_16x16x32(vf, pb, o[j]);
                }
            }
        }
    }
    float inv = 1.f / lsum;
    size_t rowbase = (size_t)(b * TT + q0w + l15) * TC + h * THD;
#pragma unroll
    for (int j = 0; j < 4; j++) {
        f16x4 ov;
#pragma unroll
        for (int rr = 0; rr < 4; rr++) ov[rr] = (f16)(o[j][rr] * inv);
        *(f16x4*)&yg[rowbase + j * 16 + quad * 4] = ov;
    }
}

// ------------------------------------------------------------------------------
extern "C" void kernel_launch(void* const* d_in, const int* in_sizes, int n_in,
                              void* d_out, int out_size, void* d_ws, size_t ws_size,
                              hipStream_t stream) {
    const float* x    = (const float*)d_in[0];
    const float* ln1w = (const float*)d_in[1];
    const float* ln1b = (const float*)d_in[2];
    const float* ln2w = (const float*)d_in[3];
    const float* ln2b = (const float*)d_in[4];
    const float* Wq   = (const float*)d_in[5];
    const float* bq   = (const float*)d_in[6];
    const float* Wk   = (const float*)d_in[7];
    const float* bk   = (const float*)d_in[8];
    const float* Wv   = (const float*)d_in[9];
    const float* bv   = (const float*)d_in[10];
    const float* Wp   = (const float*)d_in[11];
    const float* bp   = (const float*)d_in[12];
    const float* W1   = (const float*)d_in[13];
    const float* b1   = (const float*)d_in[14];
    const float* W2   = (const float*)d_in[15];
    const float* b2   = (const float*)d_in[16];

    char* ws = (char*)d_ws;
    const size_t MB = 1024 * 1024;
    f16* hb   = (f16*)(ws + 0);          // 8MB  LN1 out; reused as yb
    f16* qkv  = (f16*)(ws + 8 * MB);     // 24MB (4096 x 3072); first 8MB reused as h2b
    f16* vT   = (f16*)(ws + 32 * MB);    // 8MB
    f16* mb   = (f16*)(ws + 16 * MB);    // 32MB (16..48), reused post-attention
    f16* Wb   = (f16*)(ws + 48 * MB);    // 24MB f16 weights: Wq,Wk,Wv,Wp,W1,W2
    f16* Wqb  = Wb;                      // rows 0..3071 = fused QKV weight
    f16* Wpb  = Wb + (size_t)3 * 1024 * 1024;
    f16* W1b  = Wb + (size_t)4 * 1024 * 1024;
    f16* W2b  = Wb + (size_t)8 * 1024 * 1024;
    f16* yb   = hb;
    f16* h2b  = qkv;
    float* x1 = (float*)d_out;

    cvt_all_kernel<<<12288, 256, 0, stream>>>(Wq, Wk, Wv, Wp, W1, W2, Wb);
    ln_kernel<<<1024, 256, 0, stream>>>(x, ln1w, ln1b, hb);

    // fused QKV projection: (4096 x 1024) x (3072 x 1024)^T -> qkv
    gemm_kernel<128, 128, 3><<<dim3(3072 / 128, (TB * TT) / 128), 256, 0, stream>>>(
        hb, Wqb, bq, bk, bv, nullptr, qkv, TB * TT, 3072, TC);
    // V transpose to (B, C, T)
    transpose_kernel<<<dim3(TB * TT / 32, TC / 32), 256, 0, stream>>>(qkv, vT);
    // causal attention
    attn_kernel<<<1024, 256, 0, stream>>>(qkv, vT, yb);
    // output projection + residual -> x1 (fp32, in d_out)
    gemm_kernel<128, 64, 1><<<dim3(TC / 64, (TB * TT) / 128), 256, 0, stream>>>(
        yb, Wpb, bp, nullptr, nullptr, x, x1, TB * TT, TC, TC);
    // LN2
    ln_kernel<<<1024, 256, 0, stream>>>(x1, ln2w, ln2b, h2b);
    // MLP up + exact GELU
    gemm_kernel<128, 128, 2><<<dim3(4 * TC / 128, (TB * TT) / 128), 256, 0, stream>>>(
        h2b, W1b, b1, nullptr, nullptr, nullptr, mb, TB * TT, 4 * TC, TC);
    // MLP down + residual (in-place on d_out)
    gemm_kernel<128, 64, 1><<<dim3(TC / 64, (TB * TT) / 128), 256, 0, stream>>>(
        mb, W2b, b2, nullptr, nullptr, x1, x1, TB * TT, TC, 4 * TC);
}

// Round 5
// 392.194 us; speedup vs baseline: 1.5822x; 1.0104x over previous
//
#include <hip/hip_runtime.h>

#define TB 2
#define TT 2048
#define TC 1024
#define TH 16
#define THD 64
#define LNEPS 1e-5f

typedef _Float16 f16;
typedef __attribute__((ext_vector_type(8))) _Float16 f16x8;
typedef __attribute__((ext_vector_type(4))) _Float16 f16x4;
typedef __attribute__((ext_vector_type(4))) float f32x4;

__device__ __forceinline__ f32x4 mfma_16x16x32(f16x8 a, f16x8 b, f32x4 c) {
    return __builtin_amdgcn_mfma_f32_16x16x32_f16(a, b, c, 0, 0, 0);
}

__device__ __forceinline__ void load_lds16(const f16* g, f16* l) {
    __builtin_amdgcn_global_load_lds(
        (const __attribute__((address_space(1))) unsigned int*)g,
        (__attribute__((address_space(3))) unsigned int*)l, 16, 0, 0);
}

// ---------------- LayerNorm: fp32 in -> f16 out, one wave per row (C=1024) ----
__global__ __launch_bounds__(256) void ln_kernel(const float* __restrict__ x,
                                                 const float* __restrict__ w,
                                                 const float* __restrict__ bsrc,
                                                 f16* __restrict__ out) {
    int row  = blockIdx.x * 4 + (threadIdx.x >> 6);
    int lane = threadIdx.x & 63;
    const float4* xr = (const float4*)(x + (size_t)row * TC);
    float4 v[4];
    float s = 0.f, ss = 0.f;
#pragma unroll
    for (int i = 0; i < 4; i++) {
        v[i] = xr[i * 64 + lane];
        s  += v[i].x + v[i].y + v[i].z + v[i].w;
        ss += v[i].x * v[i].x + v[i].y * v[i].y + v[i].z * v[i].z + v[i].w * v[i].w;
    }
#pragma unroll
    for (int off = 32; off > 0; off >>= 1) {
        s  += __shfl_xor(s, off);
        ss += __shfl_xor(ss, off);
    }
    float mean = s * (1.f / TC);
    float var  = ss * (1.f / TC) - mean * mean;
    float rstd = rsqrtf(var + LNEPS);
    const float4* wv = (const float4*)w;
    const float4* bv = (const float4*)bsrc;
    f16x4* ov = (f16x4*)(out + (size_t)row * TC);
#pragma unroll
    for (int i = 0; i < 4; i++) {
        int idx = i * 64 + lane;
        float4 wc = wv[idx], bc = bv[idx];
        f16x4 o;
        o[0] = (f16)((v[i].x - mean) * rstd * wc.x + bc.x);
        o[1] = (f16)((v[i].y - mean) * rstd * wc.y + bc.y);
        o[2] = (f16)((v[i].z - mean) * rstd * wc.z + bc.z);
        o[3] = (f16)((v[i].w - mean) * rstd * wc.w + bc.w);
        ov[idx] = o;
    }
}

// ---------------- fused fp32 -> f16 weight convert ----------------------------
__global__ void cvt_all_kernel(const float* __restrict__ Wq, const float* __restrict__ Wk,
                               const float* __restrict__ Wv, const float* __restrict__ Wp,
                               const float* __restrict__ W1, const float* __restrict__ W2,
                               f16* __restrict__ dst) {
    int i = blockIdx.x * blockDim.x + threadIdx.x;  // x4 units, total 3145728
    const int Q = 262144;                           // 1M elems / 4
    const float* src;
    int j;
    int s = i >> 18;
    if (s < 4) {
        src = (s == 0) ? Wq : (s == 1) ? Wk : (s == 2) ? Wv : Wp;
        j = i & (Q - 1);
    } else if (s < 8) {
        src = W1; j = i - 4 * Q;
    } else {
        src = W2; j = i - 8 * Q;
    }
    float4 v = ((const float4*)src)[j];
    f16x4 o;
    o[0] = (f16)v.x; o[1] = (f16)v.y; o[2] = (f16)v.z; o[3] = (f16)v.w;
    ((f16x4*)dst)[i] = o;
}

// ---------------- GEMM: C[M,N] = A[M,K] * W[N,K]^T + bias (+epilogue) ---------
// EPI 0: out f16 = acc + bias
// EPI 1: out f32 = acc + bias + res
// EPI 2: out f16 = gelu_exact(acc + bias)
// EPI 3: out f16 = acc + bias-select(bq|bk|bv)  (fused QKV, N=3072)
// EPI 4: out f16 = acc (split-K partial; blockIdx.z = K-chunk, partial stride M*N)
// LDS swizzle: phys 16B-chunk(row, c) = row*4 + ((c + (row>>1)) & 3)
//   -> fragment reads are uniform 2-way bank aliases (free), staging stays
//      lane-contiguous (global_load_lds constraint) with permuted source chunk.
template <int BM, int BN, int EPI>
__global__ __launch_bounds__(256) void gemm_kernel(const f16* __restrict__ A,
                                                   const f16* __restrict__ W,
                                                   const float* __restrict__ bias,
                                                   const float* __restrict__ bias2,
                                                   const float* __restrict__ bias3,
                                                   const float* __restrict__ res,
                                                   void* __restrict__ outp,
                                                   int M, int N, int K) {
    constexpr int BK = 32;
    __shared__ __align__(16) f16 sA[BM * BK];
    __shared__ __align__(16) f16 sB[BN * BK];
    const int t  = threadIdx.x;
    const int m0 = blockIdx.y * BM;
    const int n0 = blockIdx.x * BN;
    const int wid = t >> 6, lane = t & 63;
    const int wr = wid >> 1, wc = wid & 1;
    constexpr int WM = BM / 2, WN = BN / 2;
    constexpr int MI = WM / 16, NI = WN / 16;
    int kbeg = 0, kstop = K;
    f16* pout = (f16*)outp;
    if constexpr (EPI == 4) {
        int Ks = K >> 1;
        kbeg = blockIdx.z * Ks;
        kstop = kbeg + Ks;
        pout += (size_t)blockIdx.z * M * N;
    }
    f32x4 acc[MI][NI];
#pragma unroll
    for (int i = 0; i < MI; i++)
#pragma unroll
        for (int j = 0; j < NI; j++) acc[i][j] = (f32x4){0.f, 0.f, 0.f, 0.f};
    const int quad = lane >> 4, l15 = lane & 15;

    for (int k0 = kbeg; k0 < kstop; k0 += BK) {
#pragma unroll
        for (int i = 0; i < BM * 4 / 256; i++) {
            int p = t + i * 256;
            int row = p >> 2, pc = p & 3;
            int c = (pc - (row >> 1)) & 3;          // inverse swizzle on source
            load_lds16(&A[(size_t)(m0 + row) * K + k0 + c * 8], &sA[p * 8]);
        }
#pragma unroll
        for (int i = 0; i < BN * 4 / 256; i++) {
            int p = t + i * 256;
            int row = p >> 2, pc = p & 3;
            int c = (pc - (row >> 1)) & 3;
            load_lds16(&W[(size_t)(n0 + row) * K + k0 + c * 8], &sB[p * 8]);
        }
        __syncthreads();
        f16x8 af[MI], bf[NI];
#pragma unroll
        for (int i = 0; i < MI; i++) {
            int r = wr * WM + i * 16 + l15;
            af[i] = *(const f16x8*)&sA[(r * 4 + ((quad + (r >> 1)) & 3)) * 8];
        }
#pragma unroll
        for (int j = 0; j < NI; j++) {
            int r = wc * WN + j * 16 + l15;
            bf[j] = *(const f16x8*)&sB[(r * 4 + ((quad + (r >> 1)) & 3)) * 8];
        }
#pragma unroll
        for (int i = 0; i < MI; i++)
#pragma unroll
            for (int j = 0; j < NI; j++)
                acc[i][j] = mfma_16x16x32(af[i], bf[j], acc[i][j]);
        __syncthreads();
    }

#pragma unroll
    for (int i = 0; i < MI; i++) {
#pragma unroll
        for (int j = 0; j < NI; j++) {
            int col   = n0 + wc * WN + j * 16 + l15;
            int rbase = m0 + wr * WM + i * 16 + quad * 4;
            float bvv = 0.f;
            if constexpr (EPI == 3)
                bvv = (col < 1024) ? bias[col]
                    : (col < 2048) ? bias2[col - 1024] : bias3[col - 2048];
            else if constexpr (EPI != 4)
                bvv = bias[col];
#pragma unroll
            for (int r = 0; r < 4; r++) {
                size_t idx = (size_t)(rbase + r) * N + col;
                float v = acc[i][j][r] + bvv;
                if constexpr (EPI == 0 || EPI == 3) {
                    ((f16*)outp)[idx] = (f16)v;
                } else if constexpr (EPI == 1) {
                    ((float*)outp)[idx] = v + res[idx];
                } else if constexpr (EPI == 2) {
                    ((f16*)outp)[idx] = (f16)(0.5f * v * (1.f + erff(v * 0.70710678118f)));
                } else {
                    pout[idx] = (f16)v;
                }
            }
        }
    }
}

// ---------------- split-K reduce: x1 += p0 + p1 + b2 --------------------------
__global__ __launch_bounds__(256) void reduce2_kernel(const f16* __restrict__ part,
                                                      const float* __restrict__ b2,
                                                      float* __restrict__ x1) {
    int i = blockIdx.x * 256 + threadIdx.x;     // float4 units over M*N/4 = 1M
    const f16x4* p0 = (const f16x4*)part;
    const f16x4* p1 = p0 + (1 << 20);           // +M*N/4 vectors
    f16x4 a = p0[i], b = p1[i];
    float4 r = ((float4*)x1)[i];
    float4 bb = ((const float4*)b2)[i & 255];   // N=1024 -> 256 float4/row
    r.x += (float)a[0] + (float)b[0] + bb.x;
    r.y += (float)a[1] + (float)b[1] + bb.y;
    r.z += (float)a[2] + (float)b[2] + bb.z;
    r.w += (float)a[3] + (float)b[3] + bb.w;
    ((float4*)x1)[i] = r;
}

// ---------------- V transpose: qkv v-slice (stride 3072) -> (B, C, T) f16 -----
__global__ __launch_bounds__(256) void transpose_kernel(const f16* __restrict__ in,
                                                        f16* __restrict__ out) {
    __shared__ f16 tile[32][33];
    int bt = blockIdx.x;
    int b  = bt / (TT / 32);
    int t0 = (bt % (TT / 32)) * 32;
    int c0 = blockIdx.y * 32;
    int tx = threadIdx.x & 31;
    int ty = threadIdx.x >> 5;  // 0..7
    for (int r = ty; r < 32; r += 8)
        tile[r][tx] = in[(size_t)(b * TT + t0 + r) * 3072 + 2048 + c0 + tx];
    __syncthreads();
    for (int r = ty; r < 32; r += 8)
        out[(size_t)(b * TC + c0 + r) * TT + t0 + tx] = tile[tx][r];
}

// ---------------- Block-cooperative flash attention (S^T formulation) ---------
__global__ __launch_bounds__(256, 4) void attn_kernel(const f16* __restrict__ qkv,
                                                      const f16* __restrict__ vtg,
                                                      f16* __restrict__ yg) {
    __shared__ __align__(16) f16 sK[2][64 * 64];   // phys chunk = key*8 + (dc ^ (key&7))
    __shared__ __align__(16) f16 sV[2][64 * 64];   // phys chunk = d*8 + (kc ^ (d&7))
    __shared__ __align__(16) f16 pl[4][16 * 64];   // 4e chunk = q*16 + (kq ^ ((q&7)*2))
    const int t    = threadIdx.x;
    const int wid  = t >> 6, lane = t & 63;
    const int quad = lane >> 4, l15 = lane & 15;
    const int idx = blockIdx.x;
    const int u = idx & 255, r = idx >> 8;
    const int bh = u & 31, rc = u >> 5;
    const int qblk = (r == 0) ? rc : (r == 1) ? 31 - rc : (r == 2) ? 8 + rc : 23 - rc;
    const int b = bh >> 4, h = bh & 15;
    const int q0 = qblk * 64;
    const int q0w = q0 + wid * 16;

    const f16* qptr = qkv + (size_t)(b * TT) * 3072 + h * THD;
    const f16* kptr = qptr + 1024;

    f16x8 qa0, qa1;
    {
        const f16* qb_ = qptr + (size_t)(q0w + l15) * 3072 + quad * 8;
        qa0 = *(const f16x8*)qb_;
        qa1 = *(const f16x8*)(qb_ + 32);
#pragma unroll
        for (int j = 0; j < 8; j++) { qa0[j] *= (f16)0.125f; qa1[j] *= (f16)0.125f; }
    }

    auto stage = [&](int buf, int k0) {
#pragma unroll
        for (int i = 0; i < 2; i++) {
            int p = t + i * 256;
            int row = p >> 3, c0 = p & 7;
            int cc = c0 ^ (row & 7);
            load_lds16(kptr + (size_t)(k0 + row) * 3072 + cc * 8, &sK[buf][p * 8]);
            load_lds16(vtg + (size_t)(bh * THD + row) * TT + k0 + cc * 8, &sV[buf][p * 8]);
        }
    };

    f32x4 o[4];
#pragma unroll
    for (int j = 0; j < 4; j++) o[j] = (f32x4){0.f, 0.f, 0.f, 0.f};
    float mcol = -__builtin_inff(), lsum = 0.f;
    f16* plw = pl[wid];
    const int sw = (l15 & 7) << 1;
    const int nt = qblk + 1;

    stage(0, 0);
    for (int it = 0; it < nt; it++) {
        const int cur = it & 1;
        __syncthreads();
        if (it + 1 < nt) stage(cur ^ 1, (it + 1) * 64);
        const int k0 = it * 64;
        if (k0 <= q0w + 15) {
            const f16* sk = sK[cur];
            f32x4 s[4];
#pragma unroll
            for (int g = 0; g < 4; g++) {
                int key = g * 16 + l15;
                f16x8 klo = *(const f16x8*)&sk[(key * 8 + (quad ^ (l15 & 7))) * 8];
                f16x8 khi = *(const f16x8*)&sk[(key * 8 + ((quad + 4) ^ (l15 & 7))) * 8];
                f32x4 a = (f32x4){0.f, 0.f, 0.f, 0.f};
                a = mfma_16x16x32(klo, qa0, a);
                a = mfma_16x16x32(khi, qa1, a);
                s[g] = a;
            }
            const bool full = (k0 + 63 <= q0w);
            float lm = -__builtin_inff();
#pragma unroll
            for (int g = 0; g < 4; g++) {
#pragma unroll
                for (int rr = 0; rr < 4; rr++) {
                    if (!full) {
                        int key = k0 + g * 16 + quad * 4 + rr;
                        if (key > q0w + l15) s[g][rr] = -__builtin_inff();
                    }
                    lm = fmaxf(lm, s[g][rr]);
                }
            }
            lm = fmaxf(lm, __shfl_xor(lm, 16));
            lm = fmaxf(lm, __shfl_xor(lm, 32));
            float mnew  = fmaxf(mcol, lm);
            float alpha = __expf(mcol - mnew);
            mcol = mnew;
            float sum = 0.f;
#pragma unroll
            for (int g = 0; g < 4; g++) {
                f16x4 pw;
#pragma unroll
                for (int rr = 0; rr < 4; rr++) {
                    float p = __expf(s[g][rr] - mnew);
                    sum += p;
                    pw[rr] = (f16)p;
                }
                *(f16x4*)&plw[(l15 * 16 + ((g * 4 + quad) ^ sw)) * 4] = pw;
            }
            sum += __shfl_xor(sum, 16);
            sum += __shfl_xor(sum, 32);
            lsum = lsum * alpha + sum;
#pragma unroll
            for (int j = 0; j < 4; j++) {
                o[j][0] *= alpha; o[j][1] *= alpha; o[j][2] *= alpha; o[j][3] *= alpha;
            }
            __asm__ volatile("s_waitcnt lgkmcnt(0)" ::: "memory");
            const f16* sv = sV[cur];
#pragma unroll
            for (int hh = 0; hh < 2; hh++) {
                f16x8 pb = *(const f16x8*)&plw[(l15 * 16 + ((hh * 8 + quad * 2) ^ sw)) * 4];
#pragma unroll
                for (int j = 0; j < 4; j++) {
                    int d = j * 16 + l15;
                    f16x8 vf = *(const f16x8*)&sv[(d * 8 + ((4 * hh + quad) ^ (l15 & 7))) * 8];
                    o[j] = mfma_16x16x32(vf, pb, o[j]);
                }
            }
        }
    }
    float inv = 1.f / lsum;
    size_t rowbase = (size_t)(b * TT + q0w + l15) * TC + h * THD;
#pragma unroll
    for (int j = 0; j < 4; j++) {
        f16x4 ov;
#pragma unroll
        for (int rr = 0; rr < 4; rr++) ov[rr] = (f16)(o[j][rr] * inv);
        *(f16x4*)&yg[rowbase + j * 16 + quad * 4] = ov;
    }
}

// ------------------------------------------------------------------------------
extern "C" void kernel_launch(void* const* d_in, const int* in_sizes, int n_in,
                              void* d_out, int out_size, void* d_ws, size_t ws_size,
                              hipStream_t stream) {
    const float* x    = (const float*)d_in[0];
    const float* ln1w = (const float*)d_in[1];
    const float* ln1b = (const float*)d_in[2];
    const float* ln2w = (const float*)d_in[3];
    const float* ln2b = (const float*)d_in[4];
    const float* Wq   = (const float*)d_in[5];
    const float* bq   = (const float*)d_in[6];
    const float* Wk   = (const float*)d_in[7];
    const float* bk   = (const float*)d_in[8];
    const float* Wv   = (const float*)d_in[9];
    const float* bv   = (const float*)d_in[10];
    const float* Wp   = (const float*)d_in[11];
    const float* bp   = (const float*)d_in[12];
    const float* W1   = (const float*)d_in[13];
    const float* b1   = (const float*)d_in[14];
    const float* W2   = (const float*)d_in[15];
    const float* b2   = (const float*)d_in[16];

    char* ws = (char*)d_ws;
    const size_t MB = 1024 * 1024;
    f16* hb   = (f16*)(ws + 0);          // 8MB  LN1 out; reused as yb, then partial0
    f16* qkv  = (f16*)(ws + 8 * MB);     // 24MB; first 8MB reused as h2b, then partial1
    f16* vT   = (f16*)(ws + 32 * MB);    // 8MB
    f16* mb   = (f16*)(ws + 16 * MB);    // 32MB (16..48), reused post-attention
    f16* Wb   = (f16*)(ws + 48 * MB);    // 24MB f16 weights
    f16* Wqb  = Wb;
    f16* Wpb  = Wb + (size_t)3 * 1024 * 1024;
    f16* W1b  = Wb + (size_t)4 * 1024 * 1024;
    f16* W2b  = Wb + (size_t)8 * 1024 * 1024;
    f16* yb   = hb;
    f16* h2b  = qkv;
    f16* part = hb;                      // 16MB: two 8MB f16 partials (hb+h2b regions)
    float* x1 = (float*)d_out;

    cvt_all_kernel<<<12288, 256, 0, stream>>>(Wq, Wk, Wv, Wp, W1, W2, Wb);
    ln_kernel<<<1024, 256, 0, stream>>>(x, ln1w, ln1b, hb);

    // fused QKV projection
    gemm_kernel<128, 128, 3><<<dim3(3072 / 128, (TB * TT) / 128), 256, 0, stream>>>(
        hb, Wqb, bq, bk, bv, nullptr, qkv, TB * TT, 3072, TC);
    transpose_kernel<<<dim3(TB * TT / 32, TC / 32), 256, 0, stream>>>(qkv, vT);
    attn_kernel<<<1024, 256, 0, stream>>>(qkv, vT, yb);
    // output projection + residual -> x1
    gemm_kernel<128, 64, 1><<<dim3(TC / 64, (TB * TT) / 128), 256, 0, stream>>>(
        yb, Wpb, bp, nullptr, nullptr, x, x1, TB * TT, TC, TC);
    ln_kernel<<<1024, 256, 0, stream>>>(x1, ln2w, ln2b, h2b);
    // MLP up + exact GELU
    gemm_kernel<128, 128, 2><<<dim3(4 * TC / 128, (TB * TT) / 128), 256, 0, stream>>>(
        h2b, W1b, b1, nullptr, nullptr, nullptr, mb, TB * TT, 4 * TC, TC);
    // MLP down: split-K=2 partials (f16) + reduce(+bias+residual)
    gemm_kernel<128, 128, 4><<<dim3(TC / 128, (TB * TT) / 128, 2), 256, 0, stream>>>(
        mb, W2b, nullptr, nullptr, nullptr, nullptr, part, TB * TT, TC, 4 * TC);
    reduce2_kernel<<<4096, 256, 0, stream>>>(part, b2, x1);
}

// Round 6
// 358.572 us; speedup vs baseline: 1.7305x; 1.0938x over previous
//
#include <hip/hip_runtime.h>

#define TB 2
#define TT 2048
#define TC 1024
#define TH 16
#define THD 64
#define LNEPS 1e-5f

typedef _Float16 f16;
typedef __attribute__((ext_vector_type(8))) _Float16 f16x8;
typedef __attribute__((ext_vector_type(4))) _Float16 f16x4;
typedef __attribute__((ext_vector_type(4))) float f32x4;

__device__ __forceinline__ f32x4 mfma_16x16x32(f16x8 a, f16x8 b, f32x4 c) {
    return __builtin_amdgcn_mfma_f32_16x16x32_f16(a, b, c, 0, 0, 0);
}

__device__ __forceinline__ void load_lds16(const f16* g, f16* l) {
    __builtin_amdgcn_global_load_lds(
        (const __attribute__((address_space(1))) unsigned int*)g,
        (__attribute__((address_space(3))) unsigned int*)l, 16, 0, 0);
}

// cheap tanh-form GELU: max |err| vs exact erf-GELU ~3e-3 (<< 0.1175 threshold)
__device__ __forceinline__ float gelu_fast(float v) {
    float u = 0.7978845608f * v * (1.f + 0.044715f * v * v);
    float e = __expf(2.f * u);
    return v - v / (e + 1.f);   // == 0.5v(1+tanh(u)); stable at +/-inf
}

// ---------------- LayerNorm: fp32 in -> f16 out, one wave per row (C=1024) ----
__global__ __launch_bounds__(256) void ln_kernel(const float* __restrict__ x,
                                                 const float* __restrict__ w,
                                                 const float* __restrict__ bsrc,
                                                 f16* __restrict__ out) {
    int row  = blockIdx.x * 4 + (threadIdx.x >> 6);
    int lane = threadIdx.x & 63;
    const float4* xr = (const float4*)(x + (size_t)row * TC);
    float4 v[4];
    float s = 0.f, ss = 0.f;
#pragma unroll
    for (int i = 0; i < 4; i++) {
        v[i] = xr[i * 64 + lane];
        s  += v[i].x + v[i].y + v[i].z + v[i].w;
        ss += v[i].x * v[i].x + v[i].y * v[i].y + v[i].z * v[i].z + v[i].w * v[i].w;
    }
#pragma unroll
    for (int off = 32; off > 0; off >>= 1) {
        s  += __shfl_xor(s, off);
        ss += __shfl_xor(ss, off);
    }
    float mean = s * (1.f / TC);
    float var  = ss * (1.f / TC) - mean * mean;
    float rstd = rsqrtf(var + LNEPS);
    const float4* wv = (const float4*)w;
    const float4* bv = (const float4*)bsrc;
    f16x4* ov = (f16x4*)(out + (size_t)row * TC);
#pragma unroll
    for (int i = 0; i < 4; i++) {
        int idx = i * 64 + lane;
        float4 wc = wv[idx], bc = bv[idx];
        f16x4 o;
        o[0] = (f16)((v[i].x - mean) * rstd * wc.x + bc.x);
        o[1] = (f16)((v[i].y - mean) * rstd * wc.y + bc.y);
        o[2] = (f16)((v[i].z - mean) * rstd * wc.z + bc.z);
        o[3] = (f16)((v[i].w - mean) * rstd * wc.w + bc.w);
        ov[idx] = o;
    }
}

// ---------------- fused fp32 -> f16 weight convert ----------------------------
__global__ void cvt_all_kernel(const float* __restrict__ Wq, const float* __restrict__ Wk,
                               const float* __restrict__ Wv, const float* __restrict__ Wp,
                               const float* __restrict__ W1, const float* __restrict__ W2,
                               f16* __restrict__ dst) {
    int i = blockIdx.x * blockDim.x + threadIdx.x;  // x4 units, total 3145728
    const int Q = 262144;                           // 1M elems / 4
    const float* src;
    int j;
    int s = i >> 18;
    if (s < 4) {
        src = (s == 0) ? Wq : (s == 1) ? Wk : (s == 2) ? Wv : Wp;
        j = i & (Q - 1);
    } else if (s < 8) {
        src = W1; j = i - 4 * Q;
    } else {
        src = W2; j = i - 8 * Q;
    }
    float4 v = ((const float4*)src)[j];
    f16x4 o;
    o[0] = (f16)v.x; o[1] = (f16)v.y; o[2] = (f16)v.z; o[3] = (f16)v.w;
    ((f16x4*)dst)[i] = o;
}

// ---------------- GEMM: C[M,N] = A[M,K] * W[N,K]^T + bias (+epilogue) ---------
// EPI 0: out f16 = acc + bias
// EPI 1: out f32 = acc + bias + res
// EPI 2: out f16 = gelu_fast(acc + bias)
// EPI 3: out f16 = acc + bias-select(bq|bk|bv)  (fused QKV, N=3072)
// EPI 4: out f16 = acc (split-K partial; blockIdx.z = K-chunk, partial stride M*N)
// LDS swizzle (CPR = BK/8 16B-chunks per row):
//   phys(row, c) = row*CPR + ((c + (row>>1)) & (CPR-1))
//   -> fragment reads are uniform 2-way bank aliases (free); staging stays
//      lane-contiguous (global_load_lds constraint) with permuted source chunk.
template <int BM, int BN, int BK, int EPI>
__global__ __launch_bounds__(256) void gemm_kernel(const f16* __restrict__ A,
                                                   const f16* __restrict__ W,
                                                   const float* __restrict__ bias,
                                                   const float* __restrict__ bias2,
                                                   const float* __restrict__ bias3,
                                                   const float* __restrict__ res,
                                                   void* __restrict__ outp,
                                                   int M, int N, int K) {
    constexpr int CPR = BK / 8;
    __shared__ __align__(16) f16 sA[BM * BK];
    __shared__ __align__(16) f16 sB[BN * BK];
    const int t  = threadIdx.x;
    const int m0 = blockIdx.y * BM;
    const int n0 = blockIdx.x * BN;
    const int wid = t >> 6, lane = t & 63;
    const int wr = wid >> 1, wc = wid & 1;
    constexpr int WM = BM / 2, WN = BN / 2;
    constexpr int MI = WM / 16, NI = WN / 16;
    int kbeg = 0, kstop = K;
    f16* pout = (f16*)outp;
    if constexpr (EPI == 4) {
        int Ks = K >> 1;
        kbeg = blockIdx.z * Ks;
        kstop = kbeg + Ks;
        pout += (size_t)blockIdx.z * M * N;
    }
    f32x4 acc[MI][NI];
#pragma unroll
    for (int i = 0; i < MI; i++)
#pragma unroll
        for (int j = 0; j < NI; j++) acc[i][j] = (f32x4){0.f, 0.f, 0.f, 0.f};
    const int quad = lane >> 4, l15 = lane & 15;

    for (int k0 = kbeg; k0 < kstop; k0 += BK) {
#pragma unroll
        for (int i = 0; i < BM * CPR / 256; i++) {
            int p = t + i * 256;
            int row = p / CPR, pc = p % CPR;
            int c = (pc - (row >> 1)) & (CPR - 1);   // inverse swizzle on source
            load_lds16(&A[(size_t)(m0 + row) * K + k0 + c * 8], &sA[p * 8]);
        }
#pragma unroll
        for (int i = 0; i < BN * CPR / 256; i++) {
            int p = t + i * 256;
            int row = p / CPR, pc = p % CPR;
            int c = (pc - (row >> 1)) & (CPR - 1);
            load_lds16(&W[(size_t)(n0 + row) * K + k0 + c * 8], &sB[p * 8]);
        }
        __syncthreads();
#pragma unroll
        for (int ks = 0; ks < BK / 32; ks++) {
            f16x8 af[MI], bf[NI];
#pragma unroll
            for (int i = 0; i < MI; i++) {
                int r = wr * WM + i * 16 + l15;
                af[i] = *(const f16x8*)&sA[(r * CPR + ((ks * 4 + quad + (r >> 1)) & (CPR - 1))) * 8];
            }
#pragma unroll
            for (int j = 0; j < NI; j++) {
                int r = wc * WN + j * 16 + l15;
                bf[j] = *(const f16x8*)&sB[(r * CPR + ((ks * 4 + quad + (r >> 1)) & (CPR - 1))) * 8];
            }
#pragma unroll
            for (int i = 0; i < MI; i++)
#pragma unroll
                for (int j = 0; j < NI; j++)
                    acc[i][j] = mfma_16x16x32(af[i], bf[j], acc[i][j]);
        }
        __syncthreads();
    }

#pragma unroll
    for (int i = 0; i < MI; i++) {
#pragma unroll
        for (int j = 0; j < NI; j++) {
            int col   = n0 + wc * WN + j * 16 + l15;
            int rbase = m0 + wr * WM + i * 16 + quad * 4;
            float bvv = 0.f;
            if constexpr (EPI == 3)
                bvv = (col < 1024) ? bias[col]
                    : (col < 2048) ? bias2[col - 1024] : bias3[col - 2048];
            else if constexpr (EPI != 4)
                bvv = bias[col];
#pragma unroll
            for (int r = 0; r < 4; r++) {
                size_t idx = (size_t)(rbase + r) * N + col;
                float v = acc[i][j][r] + bvv;
                if constexpr (EPI == 0 || EPI == 3) {
                    ((f16*)outp)[idx] = (f16)v;
                } else if constexpr (EPI == 1) {
                    ((float*)outp)[idx] = v + res[idx];
                } else if constexpr (EPI == 2) {
                    ((f16*)outp)[idx] = (f16)gelu_fast(v);
                } else {
                    pout[idx] = (f16)v;
                }
            }
        }
    }
}

// ---------------- split-K reduce: x1 += p0 + p1 + b2 --------------------------
__global__ __launch_bounds__(256) void reduce2_kernel(const f16* __restrict__ part,
                                                      const float* __restrict__ b2,
                                                      float* __restrict__ x1) {
    int i = blockIdx.x * 256 + threadIdx.x;     // float4 units over M*N/4 = 1M
    const f16x4* p0 = (const f16x4*)part;
    const f16x4* p1 = p0 + (1 << 20);           // +M*N/4 vectors
    f16x4 a = p0[i], b = p1[i];
    float4 r = ((float4*)x1)[i];
    float4 bb = ((const float4*)b2)[i & 255];   // N=1024 -> 256 float4/row
    r.x += (float)a[0] + (float)b[0] + bb.x;
    r.y += (float)a[1] + (float)b[1] + bb.y;
    r.z += (float)a[2] + (float)b[2] + bb.z;
    r.w += (float)a[3] + (float)b[3] + bb.w;
    ((float4*)x1)[i] = r;
}

// ---------------- V transpose: qkv v-slice (stride 3072) -> (B, C, T) f16 -----
__global__ __launch_bounds__(256) void transpose_kernel(const f16* __restrict__ in,
                                                        f16* __restrict__ out) {
    __shared__ f16 tile[32][33];
    int bt = blockIdx.x;
    int b  = bt / (TT / 32);
    int t0 = (bt % (TT / 32)) * 32;
    int c0 = blockIdx.y * 32;
    int tx = threadIdx.x & 31;
    int ty = threadIdx.x >> 5;  // 0..7
    for (int r = ty; r < 32; r += 8)
        tile[r][tx] = in[(size_t)(b * TT + t0 + r) * 3072 + 2048 + c0 + tx];
    __syncthreads();
    for (int r = ty; r < 32; r += 8)
        out[(size_t)(b * TC + c0 + r) * TT + t0 + tx] = tile[tx][r];
}

// ---------------- Block-cooperative flash attention (S^T formulation) ---------
__global__ __launch_bounds__(256, 4) void attn_kernel(const f16* __restrict__ qkv,
                                                      const f16* __restrict__ vtg,
                                                      f16* __restrict__ yg) {
    __shared__ __align__(16) f16 sK[2][64 * 64];   // phys chunk = key*8 + (dc ^ (key&7))
    __shared__ __align__(16) f16 sV[2][64 * 64];   // phys chunk = d*8 + (kc ^ (d&7))
    __shared__ __align__(16) f16 pl[4][16 * 64];   // 4e chunk = q*16 + (kq ^ ((q&7)*2))
    const int t    = threadIdx.x;
    const int wid  = t >> 6, lane = t & 63;
    const int quad = lane >> 4, l15 = lane & 15;
    const int idx = blockIdx.x;
    const int u = idx & 255, r = idx >> 8;
    const int bh = u & 31, rc = u >> 5;
    const int qblk = (r == 0) ? rc : (r == 1) ? 31 - rc : (r == 2) ? 8 + rc : 23 - rc;
    const int b = bh >> 4, h = bh & 15;
    const int q0 = qblk * 64;
    const int q0w = q0 + wid * 16;

    const f16* qptr = qkv + (size_t)(b * TT) * 3072 + h * THD;
    const f16* kptr = qptr + 1024;

    f16x8 qa0, qa1;
    {
        const f16* qb_ = qptr + (size_t)(q0w + l15) * 3072 + quad * 8;
        qa0 = *(const f16x8*)qb_;
        qa1 = *(const f16x8*)(qb_ + 32);
#pragma unroll
        for (int j = 0; j < 8; j++) { qa0[j] *= (f16)0.125f; qa1[j] *= (f16)0.125f; }
    }

    auto stage = [&](int buf, int k0) {
#pragma unroll
        for (int i = 0; i < 2; i++) {
            int p = t + i * 256;
            int row = p >> 3, c0 = p & 7;
            int cc = c0 ^ (row & 7);
            load_lds16(kptr + (size_t)(k0 + row) * 3072 + cc * 8, &sK[buf][p * 8]);
            load_lds16(vtg + (size_t)(bh * THD + row) * TT + k0 + cc * 8, &sV[buf][p * 8]);
        }
    };

    f32x4 o[4];
#pragma unroll
    for (int j = 0; j < 4; j++) o[j] = (f32x4){0.f, 0.f, 0.f, 0.f};
    float mcol = -__builtin_inff(), lsum = 0.f;
    f16* plw = pl[wid];
    const int sw = (l15 & 7) << 1;
    const int nt = qblk + 1;

    stage(0, 0);
    for (int it = 0; it < nt; it++) {
        const int cur = it & 1;
        __syncthreads();
        if (it + 1 < nt) stage(cur ^ 1, (it + 1) * 64);
        const int k0 = it * 64;
        if (k0 <= q0w + 15) {
            const f16* sk = sK[cur];
            f32x4 s[4];
#pragma unroll
            for (int g = 0; g < 4; g++) {
                int key = g * 16 + l15;
                f16x8 klo = *(const f16x8*)&sk[(key * 8 + (quad ^ (l15 & 7))) * 8];
                f16x8 khi = *(const f16x8*)&sk[(key * 8 + ((quad + 4) ^ (l15 & 7))) * 8];
                f32x4 a = (f32x4){0.f, 0.f, 0.f, 0.f};
                a = mfma_16x16x32(klo, qa0, a);
                a = mfma_16x16x32(khi, qa1, a);
                s[g] = a;
            }
            const bool full = (k0 + 63 <= q0w);
            float lm = -__builtin_inff();
#pragma unroll
            for (int g = 0; g < 4; g++) {
#pragma unroll
                for (int rr = 0; rr < 4; rr++) {
                    if (!full) {
                        int key = k0 + g * 16 + quad * 4 + rr;
                        if (key > q0w + l15) s[g][rr] = -__builtin_inff();
                    }
                    lm = fmaxf(lm, s[g][rr]);
                }
            }
            lm = fmaxf(lm, __shfl_xor(lm, 16));
            lm = fmaxf(lm, __shfl_xor(lm, 32));
            float mnew  = fmaxf(mcol, lm);
            float alpha = __expf(mcol - mnew);
            mcol = mnew;
            float sum = 0.f;
#pragma unroll
            for (int g = 0; g < 4; g++) {
                f16x4 pw;
#pragma unroll
                for (int rr = 0; rr < 4; rr++) {
                    float p = __expf(s[g][rr] - mnew);
                    sum += p;
                    pw[rr] = (f16)p;
                }
                *(f16x4*)&plw[(l15 * 16 + ((g * 4 + quad) ^ sw)) * 4] = pw;
            }
            sum += __shfl_xor(sum, 16);
            sum += __shfl_xor(sum, 32);
            lsum = lsum * alpha + sum;
#pragma unroll
            for (int j = 0; j < 4; j++) {
                o[j][0] *= alpha; o[j][1] *= alpha; o[j][2] *= alpha; o[j][3] *= alpha;
            }
            __asm__ volatile("s_waitcnt lgkmcnt(0)" ::: "memory");
            const f16* sv = sV[cur];
#pragma unroll
            for (int hh = 0; hh < 2; hh++) {
                f16x8 pb = *(const f16x8*)&plw[(l15 * 16 + ((hh * 8 + quad * 2) ^ sw)) * 4];
#pragma unroll
                for (int j = 0; j < 4; j++) {
                    int d = j * 16 + l15;
                    f16x8 vf = *(const f16x8*)&sv[(d * 8 + ((4 * hh + quad) ^ (l15 & 7))) * 8];
                    o[j] = mfma_16x16x32(vf, pb, o[j]);
                }
            }
        }
    }
    float inv = 1.f / lsum;
    size_t rowbase = (size_t)(b * TT + q0w + l15) * TC + h * THD;
#pragma unroll
    for (int j = 0; j < 4; j++) {
        f16x4 ov;
#pragma unroll
        for (int rr = 0; rr < 4; rr++) ov[rr] = (f16)(o[j][rr] * inv);
        *(f16x4*)&yg[rowbase + j * 16 + quad * 4] = ov;
    }
}

// ------------------------------------------------------------------------------
extern "C" void kernel_launch(void* const* d_in, const int* in_sizes, int n_in,
                              void* d_out, int out_size, void* d_ws, size_t ws_size,
                              hipStream_t stream) {
    const float* x    = (const float*)d_in[0];
    const float* ln1w = (const float*)d_in[1];
    const float* ln1b = (const float*)d_in[2];
    const float* ln2w = (const float*)d_in[3];
    const float* ln2b = (const float*)d_in[4];
    const float* Wq   = (const float*)d_in[5];
    const float* bq   = (const float*)d_in[6];
    const float* Wk   = (const float*)d_in[7];
    const float* bk   = (const float*)d_in[8];
    const float* Wv   = (const float*)d_in[9];
    const float* bv   = (const float*)d_in[10];
    const float* Wp   = (const float*)d_in[11];
    const float* bp   = (const float*)d_in[12];
    const float* W1   = (const float*)d_in[13];
    const float* b1   = (const float*)d_in[14];
    const float* W2   = (const float*)d_in[15];
    const float* b2   = (const float*)d_in[16];

    char* ws = (char*)d_ws;
    const size_t MB = 1024 * 1024;
    f16* hb   = (f16*)(ws + 0);          // 8MB  LN1 out; reused as yb, then partial0
    f16* qkv  = (f16*)(ws + 8 * MB);     // 24MB; first 8MB reused as h2b, then partial1
    f16* vT   = (f16*)(ws + 32 * MB);    // 8MB
    f16* mb   = (f16*)(ws + 16 * MB);    // 32MB (16..48), reused post-attention
    f16* Wb   = (f16*)(ws + 48 * MB);    // 24MB f16 weights
    f16* Wqb  = Wb;
    f16* Wpb  = Wb + (size_t)3 * 1024 * 1024;
    f16* W1b  = Wb + (size_t)4 * 1024 * 1024;
    f16* W2b  = Wb + (size_t)8 * 1024 * 1024;
    f16* yb   = hb;
    f16* h2b  = qkv;
    f16* part = hb;                      // 16MB: two 8MB f16 partials (hb+h2b regions)
    float* x1 = (float*)d_out;

    cvt_all_kernel<<<12288, 256, 0, stream>>>(Wq, Wk, Wv, Wp, W1, W2, Wb);
    ln_kernel<<<1024, 256, 0, stream>>>(x, ln1w, ln1b, hb);

    // fused QKV projection
    gemm_kernel<128, 128, 64, 3><<<dim3(3072 / 128, (TB * TT) / 128), 256, 0, stream>>>(
        hb, Wqb, bq, bk, bv, nullptr, qkv, TB * TT, 3072, TC);
    transpose_kernel<<<dim3(TB * TT / 32, TC / 32), 256, 0, stream>>>(qkv, vT);
    attn_kernel<<<1024, 256, 0, stream>>>(qkv, vT, yb);
    // output projection + residual -> x1
    gemm_kernel<128, 64, 64, 1><<<dim3(TC / 64, (TB * TT) / 128), 256, 0, stream>>>(
        yb, Wpb, bp, nullptr, nullptr, x, x1, TB * TT, TC, TC);
    ln_kernel<<<1024, 256, 0, stream>>>(x1, ln2w, ln2b, h2b);
    // MLP up + fast GELU
    gemm_kernel<128, 128, 64, 2><<<dim3(4 * TC / 128, (TB * TT) / 128), 256, 0, stream>>>(
        h2b, W1b, b1, nullptr, nullptr, nullptr, mb, TB * TT, 4 * TC, TC);
    // MLP down: split-K=2 partials (f16) + reduce(+bias+residual)
    gemm_kernel<128, 128, 64, 4><<<dim3(TC / 128, (TB * TT) / 128, 2), 256, 0, stream>>>(
        mb, W2b, nullptr, nullptr, nullptr, nullptr, part, TB * TT, TC, 4 * TC);
    reduce2_kernel<<<4096, 256, 0, stream>>>(part, b2, x1);
}